// Round 4
// baseline (2702.018 us; speedup 1.0000x reference)
//
#include <hip/hip_runtime.h>
#include <hip/hip_bf16.h>
#include <math.h>

// Problem constants
#define Hh   128          // hidden size
#define G4H  512          // 4*H
#define Bb   256          // batch
#define Tt   512          // seq len
#define INL0 64           // layer-0 input size

// ---------------- activation helper ----------------
__device__ __forceinline__ float sigmoid_f(float x) {
    return 1.0f / (1.0f + __expf(-x));
}

// ---------------- xg GEMM ----------------
// xg[mc, g] = sum_k A[row(mc), k] * W[g, k] + bih[g] + bhh[g]
// A is [B*T, K] row-major; chunk row mc = b*Tc + tl -> global row b*T + t0 + tl.
// Tile: BM=128 x BN=128, BK=32, 256 threads, 8x8 micro-tile.
#define BM 128
#define BN 128
#define BK 32

__global__ __launch_bounds__(256) void xg_gemm(
    const float* __restrict__ A, const float* __restrict__ W,
    const float* __restrict__ bih, const float* __restrict__ bhh,
    float* __restrict__ xg, int K, int Tc, int t0)
{
    __shared__ float As[BK][BM + 4];
    __shared__ float Bs[BK][BN + 4];

    const int tid = threadIdx.x;
    const int tx  = tid & 15;
    const int ty  = tid >> 4;
    const int mc0 = blockIdx.x * BM;
    const int n0  = blockIdx.y * BN;

    const int la_r = tid >> 3;          // 0..31
    const int la_c = (tid & 7) * 4;     // 0,4,...,28

    const float* aptr[4];
    const float* wptr[4];
#pragma unroll
    for (int p = 0; p < 4; ++p) {
        int rc = mc0 + la_r + p * 32;       // chunk row
        int bb = rc / Tc;
        int tl = rc - bb * Tc;
        aptr[p] = A + (size_t)(bb * Tt + t0 + tl) * K + la_c;
        wptr[p] = W + (size_t)(n0 + la_r + p * 32) * K + la_c;
    }

    float acc[8][8];
#pragma unroll
    for (int i = 0; i < 8; ++i)
#pragma unroll
        for (int j = 0; j < 8; ++j) acc[i][j] = 0.0f;

    for (int k0 = 0; k0 < K; k0 += BK) {
#pragma unroll
        for (int p = 0; p < 4; ++p) {
            float4 av = *(const float4*)(aptr[p] + k0);
            int r = la_r + p * 32;
            As[la_c + 0][r] = av.x;
            As[la_c + 1][r] = av.y;
            As[la_c + 2][r] = av.z;
            As[la_c + 3][r] = av.w;
            float4 wv = *(const float4*)(wptr[p] + k0);
            Bs[la_c + 0][r] = wv.x;
            Bs[la_c + 1][r] = wv.y;
            Bs[la_c + 2][r] = wv.z;
            Bs[la_c + 3][r] = wv.w;
        }
        __syncthreads();

#pragma unroll 8
        for (int k = 0; k < BK; ++k) {
            float4 a0 = *(const float4*)&As[k][ty * 8];
            float4 a1 = *(const float4*)&As[k][ty * 8 + 4];
            float4 b0 = *(const float4*)&Bs[k][tx * 8];
            float4 b1 = *(const float4*)&Bs[k][tx * 8 + 4];
            float av[8] = {a0.x, a0.y, a0.z, a0.w, a1.x, a1.y, a1.z, a1.w};
            float bv[8] = {b0.x, b0.y, b0.z, b0.w, b1.x, b1.y, b1.z, b1.w};
#pragma unroll
            for (int i = 0; i < 8; ++i)
#pragma unroll
                for (int j = 0; j < 8; ++j)
                    acc[i][j] = fmaf(av[i], bv[j], acc[i][j]);
        }
        __syncthreads();
    }

    const int row0 = mc0 + ty * 8;
    const int col0 = n0 + tx * 8;
    float bias[8];
#pragma unroll
    for (int j = 0; j < 8; ++j) bias[j] = bih[col0 + j] + bhh[col0 + j];
#pragma unroll
    for (int i = 0; i < 8; ++i) {
        float4 v0 = {acc[i][0] + bias[0], acc[i][1] + bias[1],
                     acc[i][2] + bias[2], acc[i][3] + bias[3]};
        float4 v1 = {acc[i][4] + bias[4], acc[i][5] + bias[5],
                     acc[i][6] + bias[6], acc[i][7] + bias[7]};
        float* dst = xg + (size_t)(row0 + i) * G4H + col0;
        *(float4*)(dst)     = v0;
        *(float4*)(dst + 4) = v1;
    }
}

// ---------------- recurrent kernel ----------------
// One block per batch row.  1024 threads = 16 waves (4 waves/SIMD).
// Thread mapping (wave = tid>>6, lane = tid&63):
//   gate g = lane>>4 (0:i 1:f 2:g 3:o), idx = (lane>>1)&7, half = lane&1
//   unit u = wave*8 + idx (0..127), Whh row r = g*128 + u.
// Each thread holds HALF a Whh row: 64 floats = 16 NAMED float4 (64 VGPRs),
// guaranteeing register residency (round-2 profile showed VGPR=84 => the
// 128-reg version was re-loading Whh from L2 every step: 34 GB/layer).
// Halves combine via __shfl_xor(1); gates gather via 3 in-wave __shfl.
// h double-buffered in LDS -> exactly ONE barrier per timestep.
__global__ __launch_bounds__(1024, 4) void lstm_recur(
    const float* __restrict__ xg,    // [B, Tc, 4H] chunk
    const float* __restrict__ Whh,   // [4H, H]
    float* __restrict__ out,         // [B, T, H] layer output base
    float* __restrict__ h_state, float* __restrict__ c_state,
    int Tc, int t0, int first_chunk,
    float* __restrict__ hn_dst, float* __restrict__ cn_dst,
    float* __restrict__ htop_dst)
{
    __shared__ float hs[2][Hh];

    const int b    = blockIdx.x;
    const int tid  = threadIdx.x;
    const int wave = tid >> 6;
    const int lane = tid & 63;
    const int g    = lane >> 4;          // gate 0..3
    const int idx  = (lane >> 1) & 7;
    const int half = lane & 1;
    const int u    = wave * 8 + idx;     // hidden unit 0..127
    const int r    = g * Hh + u;         // Whh row

    // persistent weights: half-row of Whh, 16 named float4 (64 VGPRs)
    const float* wp = Whh + (size_t)r * Hh + half * 64;
    float4 w0  = *(const float4*)(wp +  0), w1  = *(const float4*)(wp +  4);
    float4 w2  = *(const float4*)(wp +  8), w3  = *(const float4*)(wp + 12);
    float4 w4  = *(const float4*)(wp + 16), w5  = *(const float4*)(wp + 20);
    float4 w6  = *(const float4*)(wp + 24), w7  = *(const float4*)(wp + 28);
    float4 w8  = *(const float4*)(wp + 32), w9  = *(const float4*)(wp + 36);
    float4 w10 = *(const float4*)(wp + 40), w11 = *(const float4*)(wp + 44);
    float4 w12 = *(const float4*)(wp + 48), w13 = *(const float4*)(wp + 52);
    float4 w14 = *(const float4*)(wp + 56), w15 = *(const float4*)(wp + 60);

    float c = 0.0f, hlast = 0.0f;
    if (g == 0) {
        float h0 = 0.0f;
        if (!first_chunk) {
            h0 = h_state[b * Hh + u];
            c  = c_state[b * Hh + u];
        }
        if (half == 0) hs[0][u] = h0;
    }
    __syncthreads();

    const float* xgrow = xg + (size_t)b * Tc * G4H + r;
    float* orow = out + ((size_t)b * Tt + t0) * Hh + u;
    float cur = xgrow[0];

    for (int s = 0; s < Tc; ++s) {
        const int p = s & 1;
        // prefetch next step's xg under the dot product (clamped, branchless)
        int snxt = (s + 1 < Tc) ? (s + 1) : s;
        float nxt = xgrow[(size_t)snxt * G4H];

        const float* hb = &hs[p][half * 64];
        float a0 = 0.f, a1 = 0.f, a2 = 0.f, a3 = 0.f;
#define DOT(J, W) { float4 hv = *(const float4*)(hb + (J)*4);      \
                    a0 = fmaf((W).x, hv.x, a0);                    \
                    a1 = fmaf((W).y, hv.y, a1);                    \
                    a2 = fmaf((W).z, hv.z, a2);                    \
                    a3 = fmaf((W).w, hv.w, a3); }
        DOT(0,w0)  DOT(1,w1)  DOT(2,w2)  DOT(3,w3)
        DOT(4,w4)  DOT(5,w5)  DOT(6,w6)  DOT(7,w7)
        DOT(8,w8)  DOT(9,w9)  DOT(10,w10) DOT(11,w11)
        DOT(12,w12) DOT(13,w13) DOT(14,w14) DOT(15,w15)
#undef DOT
        float part = (a0 + a1) + (a2 + a3);
        float pre  = cur + part + __shfl_xor(part, 1);

        // branchless activation: g-gate uses tanh(x) = 2*sigmoid(2x)-1
        float px  = (g == 2) ? 2.0f * pre : pre;
        float sg  = sigmoid_f(px);
        float act = (g == 2) ? 2.0f * sg - 1.0f : sg;

        // gather f,g,o into the i-lanes (same wave): lane base keeps idx+half
        int base = lane & 15;
        float fv = __shfl(act, base + 16);
        float gv = __shfl(act, base + 32);
        float ov = __shfl(act, base + 48);

        if (g == 0) {   // both halves compute (identical); half 0 stores
            c = fmaf(fv, c, act * gv);
            float th = 2.0f * sigmoid_f(2.0f * c) - 1.0f;   // tanh(c)
            float h  = ov * th;
            hlast = h;
            if (half == 0) {
                hs[p ^ 1][u] = h;
                orow[(size_t)s * Hh] = h;
            }
        }
        __syncthreads();   // hs[p^1] visible; fences next write to hs[p]
        cur = nxt;
    }

    if (g == 0 && half == 0) {
        h_state[b * Hh + u] = hlast;
        c_state[b * Hh + u] = c;
        if (hn_dst) {
            hn_dst[b * Hh + u] = hlast;
            cn_dst[b * Hh + u] = c;
            if (htop_dst) htop_dst[b * Hh + u] = hlast;
        }
    }
}

// ---------------- host launch ----------------
extern "C" void kernel_launch(void* const* d_in, const int* in_sizes, int n_in,
                              void* d_out, int out_size, void* d_ws, size_t ws_size,
                              hipStream_t stream)
{
    const float* x = (const float*)d_in[0];
    const float* Wih[3] = {(const float*)d_in[1], (const float*)d_in[5], (const float*)d_in[9]};
    const float* Whh[3] = {(const float*)d_in[2], (const float*)d_in[6], (const float*)d_in[10]};
    const float* bih[3] = {(const float*)d_in[3], (const float*)d_in[7], (const float*)d_in[11]};
    const float* bhh[3] = {(const float*)d_in[4], (const float*)d_in[8], (const float*)d_in[12]};

    // d_out layout: out[B,T,H] | h_top[B,H] | h_n[3,B,H] | c_n[3,B,H]
    float* out_final = (float*)d_out;
    const size_t OUT_ELEMS = (size_t)Bb * Tt * Hh;       // 16,777,216
    float* htop = out_final + OUT_ELEMS;
    float* hn   = htop + (size_t)Bb * Hh;
    float* cn   = hn + (size_t)3 * Bb * Hh;

    // workspace: h_state | c_state | xg_chunk   (all layers run in-place on out_final)
    float* ws      = (float*)d_ws;
    float* h_state = ws;
    float* c_state = h_state + (size_t)Bb * Hh;
    float* xgbuf   = c_state + (size_t)Bb * Hh;

    // adaptive chunk size so xg fits in workspace
    size_t base_bytes = 2 * (size_t)Bb * Hh * sizeof(float);
    int Tc = Tt;
    while (Tc > 32 &&
           base_bytes + (size_t)Bb * Tc * G4H * sizeof(float) > ws_size)
        Tc >>= 1;

    for (int layer = 0; layer < 3; ++layer) {
        const float* in_ptr = (layer == 0) ? x : out_final;
        const int    K      = (layer == 0) ? INL0 : Hh;
        // In-place is safe per chunk: the GEMM for rows [t0,t0+Tc) completes
        // (stream order) before the recurrence overwrites exactly those rows,
        // and later chunks read rows the recurrence hasn't touched yet.

        for (int t0 = 0; t0 < Tt; t0 += Tc) {
            dim3 ggrid((Bb * Tc) / BM, G4H / BN);
            xg_gemm<<<ggrid, 256, 0, stream>>>(
                in_ptr, Wih[layer], bih[layer], bhh[layer], xgbuf, K, Tc, t0);

            bool last = (t0 + Tc >= Tt);
            lstm_recur<<<Bb, 1024, 0, stream>>>(
                xgbuf, Whh[layer], out_final, h_state, c_state,
                Tc, t0, (t0 == 0) ? 1 : 0,
                last ? (hn + (size_t)layer * Bb * Hh) : nullptr,
                last ? (cn + (size_t)layer * Bb * Hh) : nullptr,
                (last && layer == 2) ? htop : nullptr);
        }
    }
}

// Round 6
// 2030.944 us; speedup vs baseline: 1.3304x; 1.3304x over previous
//
#include <hip/hip_runtime.h>
#include <hip/hip_bf16.h>
#include <math.h>

// Problem constants
#define Hh   128          // hidden size
#define G4H  512          // 4*H
#define Bb   256          // batch
#define Tt   512          // seq len
#define INL0 64           // layer-0 input size

// ---------------- activation helper ----------------
__device__ __forceinline__ float sigmoid_f(float x) {
    return 1.0f / (1.0f + __expf(-x));
}

// ---------------- xg GEMM ----------------
// xg[mc, g] = sum_k A[row(mc), k] * W[g, k] + bih[g] + bhh[g]
// A is [B*T, K] row-major; chunk row mc = b*Tc + tl -> global row b*T + t0 + tl.
// Tile: BM=128 x BN=128, BK=32, 256 threads, 8x8 micro-tile.
#define BM 128
#define BN 128
#define BK 32

__global__ __launch_bounds__(256) void xg_gemm(
    const float* __restrict__ A, const float* __restrict__ W,
    const float* __restrict__ bih, const float* __restrict__ bhh,
    float* __restrict__ xg, int K, int Tc, int t0)
{
    __shared__ float As[BK][BM + 4];
    __shared__ float Bs[BK][BN + 4];

    const int tid = threadIdx.x;
    const int tx  = tid & 15;
    const int ty  = tid >> 4;
    const int mc0 = blockIdx.x * BM;
    const int n0  = blockIdx.y * BN;

    const int la_r = tid >> 3;          // 0..31
    const int la_c = (tid & 7) * 4;     // 0,4,...,28

    const float* aptr[4];
    const float* wptr[4];
#pragma unroll
    for (int p = 0; p < 4; ++p) {
        int rc = mc0 + la_r + p * 32;       // chunk row
        int bb = rc / Tc;
        int tl = rc - bb * Tc;
        aptr[p] = A + (size_t)(bb * Tt + t0 + tl) * K + la_c;
        wptr[p] = W + (size_t)(n0 + la_r + p * 32) * K + la_c;
    }

    float acc[8][8];
#pragma unroll
    for (int i = 0; i < 8; ++i)
#pragma unroll
        for (int j = 0; j < 8; ++j) acc[i][j] = 0.0f;

    for (int k0 = 0; k0 < K; k0 += BK) {
#pragma unroll
        for (int p = 0; p < 4; ++p) {
            float4 av = *(const float4*)(aptr[p] + k0);
            int r = la_r + p * 32;
            As[la_c + 0][r] = av.x;
            As[la_c + 1][r] = av.y;
            As[la_c + 2][r] = av.z;
            As[la_c + 3][r] = av.w;
            float4 wv = *(const float4*)(wptr[p] + k0);
            Bs[la_c + 0][r] = wv.x;
            Bs[la_c + 1][r] = wv.y;
            Bs[la_c + 2][r] = wv.z;
            Bs[la_c + 3][r] = wv.w;
        }
        __syncthreads();

#pragma unroll 8
        for (int k = 0; k < BK; ++k) {
            float4 a0 = *(const float4*)&As[k][ty * 8];
            float4 a1 = *(const float4*)&As[k][ty * 8 + 4];
            float4 b0 = *(const float4*)&Bs[k][tx * 8];
            float4 b1 = *(const float4*)&Bs[k][tx * 8 + 4];
            float av[8] = {a0.x, a0.y, a0.z, a0.w, a1.x, a1.y, a1.z, a1.w};
            float bv[8] = {b0.x, b0.y, b0.z, b0.w, b1.x, b1.y, b1.z, b1.w};
#pragma unroll
            for (int i = 0; i < 8; ++i)
#pragma unroll
                for (int j = 0; j < 8; ++j)
                    acc[i][j] = fmaf(av[i], bv[j], acc[i][j]);
        }
        __syncthreads();
    }

    const int row0 = mc0 + ty * 8;
    const int col0 = n0 + tx * 8;
    float bias[8];
#pragma unroll
    for (int j = 0; j < 8; ++j) bias[j] = bih[col0 + j] + bhh[col0 + j];
#pragma unroll
    for (int i = 0; i < 8; ++i) {
        float4 v0 = {acc[i][0] + bias[0], acc[i][1] + bias[1],
                     acc[i][2] + bias[2], acc[i][3] + bias[3]};
        float4 v1 = {acc[i][4] + bias[4], acc[i][5] + bias[5],
                     acc[i][6] + bias[6], acc[i][7] + bias[7]};
        float* dst = xg + (size_t)(row0 + i) * G4H + col0;
        *(float4*)(dst)     = v0;
        *(float4*)(dst + 4) = v1;
    }
}

// ---------------- recurrent kernel ----------------
// One block per batch row.  512 threads = 8 waves (2 waves/SIMD).
// Thread mapping (wave = tid>>6, lane = tid&63):
//   unit u = wave*16 + (lane&15)   (hidden index, 0..127)
//   gate g = lane>>4               (0:i 1:f 2:g 3:o)
//   Whh row r = g*128 + u.
// Each thread holds a FULL Whh row: 128 floats = 32 NAMED float4 = 128 VGPRs.
// Register-budget arithmetic (round-4 post-mortem): 1024-thr blocks cap the
// allocator at 128 VGPRs -> weight loads got sunk into the loop (VGPR=48,
// L2 refetch every step). 512-thr blocks + __launch_bounds__(512,2) give a
// 256-VGPR budget; dot-product is split into 4 groups of 8 float4s with
// sched_barrier(0) between, capping live LDS temps at 32 regs:
// peak ~ 128(w) + 32(hv) + ~30(misc) ~ 190 < 256, and 190 regs still allows
// the declared 2 waves/SIMD -> no reason to sink.
// LDS h reads are PURE BROADCAST (all 64 lanes same address) -> zero bank
// conflicts (round 4's half-split cost 1.3e8 conflict cycles).
// All 4 gates of unit u live in ONE wave -> 3 in-wave __shfl gather.
// h double-buffered in LDS -> exactly ONE barrier per timestep.
__global__ __launch_bounds__(512, 2) void lstm_recur(
    const float* __restrict__ xg,    // [B, Tc, 4H] chunk
    const float* __restrict__ Whh,   // [4H, H]
    float* __restrict__ out,         // [B, T, H] layer output base
    float* __restrict__ h_state, float* __restrict__ c_state,
    int Tc, int t0, int first_chunk,
    float* __restrict__ hn_dst, float* __restrict__ cn_dst,
    float* __restrict__ htop_dst)
{
    __shared__ float hs[2][Hh];

    const int b    = blockIdx.x;
    const int tid  = threadIdx.x;
    const int lane = tid & 63;
    const int u    = (tid >> 6) * 16 + (lane & 15);
    const int g    = lane >> 4;
    const int r    = g * Hh + u;
    const bool is_i = (g == 0);

    // persistent weights: full Whh row, 32 named float4 (128 VGPRs)
    const float* wp = Whh + (size_t)r * Hh;
    float4 w0  = *(const float4*)(wp +   0), w1  = *(const float4*)(wp +   4);
    float4 w2  = *(const float4*)(wp +   8), w3  = *(const float4*)(wp +  12);
    float4 w4  = *(const float4*)(wp +  16), w5  = *(const float4*)(wp +  20);
    float4 w6  = *(const float4*)(wp +  24), w7  = *(const float4*)(wp +  28);
    float4 w8  = *(const float4*)(wp +  32), w9  = *(const float4*)(wp +  36);
    float4 w10 = *(const float4*)(wp +  40), w11 = *(const float4*)(wp +  44);
    float4 w12 = *(const float4*)(wp +  48), w13 = *(const float4*)(wp +  52);
    float4 w14 = *(const float4*)(wp +  56), w15 = *(const float4*)(wp +  60);
    float4 w16 = *(const float4*)(wp +  64), w17 = *(const float4*)(wp +  68);
    float4 w18 = *(const float4*)(wp +  72), w19 = *(const float4*)(wp +  76);
    float4 w20 = *(const float4*)(wp +  80), w21 = *(const float4*)(wp +  84);
    float4 w22 = *(const float4*)(wp +  88), w23 = *(const float4*)(wp +  92);
    float4 w24 = *(const float4*)(wp +  96), w25 = *(const float4*)(wp + 100);
    float4 w26 = *(const float4*)(wp + 104), w27 = *(const float4*)(wp + 108);
    float4 w28 = *(const float4*)(wp + 112), w29 = *(const float4*)(wp + 116);
    float4 w30 = *(const float4*)(wp + 120), w31 = *(const float4*)(wp + 124);

    float c = 0.0f, hlast = 0.0f;
    if (is_i) {
        float h0 = 0.0f;
        if (!first_chunk) {
            h0 = h_state[b * Hh + u];
            c  = c_state[b * Hh + u];
        }
        hs[0][u] = h0;
    }
    __syncthreads();

    const float* xgrow = xg + (size_t)b * Tc * G4H + r;
    float* orow = out + ((size_t)b * Tt + t0) * Hh + u;
    float cur = xgrow[0];

    for (int s = 0; s < Tc; ++s) {
        const int p = s & 1;
        // prefetch next step's xg under the dot product (clamped, branchless)
        int snxt = (s + 1 < Tc) ? (s + 1) : s;
        float nxt = xgrow[(size_t)snxt * G4H];

        const float* hb = &hs[p][0];
        float a0 = 0.f, a1 = 0.f, a2 = 0.f, a3 = 0.f;
#define DOT(J, W) { float4 hv = *(const float4*)(hb + (J)*4);      \
                    a0 = fmaf((W).x, hv.x, a0);                    \
                    a1 = fmaf((W).y, hv.y, a1);                    \
                    a2 = fmaf((W).z, hv.z, a2);                    \
                    a3 = fmaf((W).w, hv.w, a3); }
        DOT(0,w0)   DOT(1,w1)   DOT(2,w2)   DOT(3,w3)
        DOT(4,w4)   DOT(5,w5)   DOT(6,w6)   DOT(7,w7)
        __builtin_amdgcn_sched_barrier(0);   // cap live hv temps at 8 float4
        DOT(8,w8)   DOT(9,w9)   DOT(10,w10) DOT(11,w11)
        DOT(12,w12) DOT(13,w13) DOT(14,w14) DOT(15,w15)
        __builtin_amdgcn_sched_barrier(0);
        DOT(16,w16) DOT(17,w17) DOT(18,w18) DOT(19,w19)
        DOT(20,w20) DOT(21,w21) DOT(22,w22) DOT(23,w23)
        __builtin_amdgcn_sched_barrier(0);
        DOT(24,w24) DOT(25,w25) DOT(26,w26) DOT(27,w27)
        DOT(28,w28) DOT(29,w29) DOT(30,w30) DOT(31,w31)
#undef DOT
        float pre = cur + ((a0 + a1) + (a2 + a3));

        // branchless activation: g-gate uses tanh(x) = 2*sigmoid(2x)-1
        float px  = (g == 2) ? 2.0f * pre : pre;
        float sg  = sigmoid_f(px);
        float act = (g == 2) ? 2.0f * sg - 1.0f : sg;

        // gather f,g,o into the i-lanes (same wave)
        int base = lane & 15;
        float fv = __shfl(act, base + 16);
        float gv = __shfl(act, base + 32);
        float ov = __shfl(act, base + 48);

        if (is_i) {
            c = fmaf(fv, c, act * gv);                      // act == i-gate
            float th = 2.0f * sigmoid_f(2.0f * c) - 1.0f;   // tanh(c)
            float h  = ov * th;
            hlast = h;
            hs[p ^ 1][u] = h;
            orow[(size_t)s * Hh] = h;
        }
        __syncthreads();   // hs[p^1] visible; fences next write to hs[p]
        cur = nxt;
    }

    if (is_i) {
        h_state[b * Hh + u] = hlast;
        c_state[b * Hh + u] = c;
        if (hn_dst) {
            hn_dst[b * Hh + u] = hlast;
            cn_dst[b * Hh + u] = c;
            if (htop_dst) htop_dst[b * Hh + u] = hlast;
        }
    }
}

// ---------------- host launch ----------------
extern "C" void kernel_launch(void* const* d_in, const int* in_sizes, int n_in,
                              void* d_out, int out_size, void* d_ws, size_t ws_size,
                              hipStream_t stream)
{
    const float* x = (const float*)d_in[0];
    const float* Wih[3] = {(const float*)d_in[1], (const float*)d_in[5], (const float*)d_in[9]};
    const float* Whh[3] = {(const float*)d_in[2], (const float*)d_in[6], (const float*)d_in[10]};
    const float* bih[3] = {(const float*)d_in[3], (const float*)d_in[7], (const float*)d_in[11]};
    const float* bhh[3] = {(const float*)d_in[4], (const float*)d_in[8], (const float*)d_in[12]};

    // d_out layout: out[B,T,H] | h_top[B,H] | h_n[3,B,H] | c_n[3,B,H]
    float* out_final = (float*)d_out;
    const size_t OUT_ELEMS = (size_t)Bb * Tt * Hh;       // 16,777,216
    float* htop = out_final + OUT_ELEMS;
    float* hn   = htop + (size_t)Bb * Hh;
    float* cn   = hn + (size_t)3 * Bb * Hh;

    // workspace: h_state | c_state | xg_chunk   (all layers run in-place on out_final)
    float* ws      = (float*)d_ws;
    float* h_state = ws;
    float* c_state = h_state + (size_t)Bb * Hh;
    float* xgbuf   = c_state + (size_t)Bb * Hh;

    // adaptive chunk size so xg fits in workspace
    size_t base_bytes = 2 * (size_t)Bb * Hh * sizeof(float);
    int Tc = Tt;
    while (Tc > 32 &&
           base_bytes + (size_t)Bb * Tc * G4H * sizeof(float) > ws_size)
        Tc >>= 1;

    for (int layer = 0; layer < 3; ++layer) {
        const float* in_ptr = (layer == 0) ? x : out_final;
        const int    K      = (layer == 0) ? INL0 : Hh;
        // In-place is safe per chunk: the GEMM for rows [t0,t0+Tc) completes
        // (stream order) before the recurrence overwrites exactly those rows,
        // and later chunks read rows the recurrence hasn't touched yet.

        for (int t0 = 0; t0 < Tt; t0 += Tc) {
            dim3 ggrid((Bb * Tc) / BM, G4H / BN);
            xg_gemm<<<ggrid, 256, 0, stream>>>(
                in_ptr, Wih[layer], bih[layer], bhh[layer], xgbuf, K, Tc, t0);

            bool last = (t0 + Tc >= Tt);
            lstm_recur<<<Bb, 512, 0, stream>>>(
                xgbuf, Whh[layer], out_final, h_state, c_state,
                Tc, t0, (t0 == 0) ? 1 : 0,
                last ? (hn + (size_t)layer * Bb * Hh) : nullptr,
                last ? (cn + (size_t)layer * Bb * Hh) : nullptr,
                (last && layer == 2) ? htop : nullptr);
        }
    }
}